// Round 1
// baseline (557.661 us; speedup 1.0000x reference)
//
#include <hip/hip_runtime.h>

// Problem constants
#define Bsz 16
#define Dch 1024
#define Tsz 1024
#define Hsz 1024
#define Mtot (Bsz*Tsz)   // 16384
#define K2   (2*Dch)     // 2048
#define Ntot (3*Hsz)     // 3072

typedef __attribute__((ext_vector_type(8))) short bf16x8;
typedef __attribute__((ext_vector_type(4))) float f32x4;
typedef __attribute__((ext_vector_type(8))) unsigned short u16x8;

__device__ __forceinline__ unsigned short f2bf(float x) {
    unsigned u = __float_as_uint(x);
    u += 0x7FFFu + ((u >> 16) & 1u);   // round-to-nearest-even
    return (unsigned short)(u >> 16);
}
__device__ __forceinline__ float bf2f(unsigned short s) {
    return __uint_as_float(((unsigned)s) << 16);
}

// conv_w [3072,1024,2] fp32 -> bf16. Flat layout IS B^T[n][kk] row-major already.
__global__ void prep_w(const float* __restrict__ w, unsigned short* __restrict__ wb) {
    int i = blockIdx.x * blockDim.x + threadIdx.x;   // one float4 per thread
    float4 v = ((const float4*)w)[i];
    ushort4 r;
    r.x = f2bf(v.x); r.y = f2bf(v.y); r.z = f2bf(v.z); r.w = f2bf(v.w);
    ((ushort4*)wb)[i] = r;
}

// inputs [B,D,T] fp32 -> A2 [M=B*T][2048] bf16, A2[b*T+t][2d+k] = x[b,d,t+k-1] (0 at t-1<0)
// LDS-transpose: 64 d-rows x (64+1) t-cols per block.
__global__ void prep_a(const float* __restrict__ x, unsigned short* __restrict__ a2) {
    __shared__ float Xs[64][66];
    int bid = blockIdx.x;
    int b   = bid >> 8;
    int tt0 = ((bid >> 4) & 15) << 6;
    int dd0 = (bid & 15) << 6;
    int tid  = threadIdx.x;
    int colt = tid & 63, rowq = tid >> 6;
    const size_t xbase = (size_t)b * (Dch * Tsz);
    #pragma unroll
    for (int r = 0; r < 16; r++) {
        int dd = r * 4 + rowq;
        Xs[dd][1 + colt] = x[xbase + (size_t)(dd0 + dd) * Tsz + tt0 + colt];
    }
    if (tid < 64) {
        Xs[tid][0] = (tt0 == 0) ? 0.f : x[xbase + (size_t)(dd0 + tid) * Tsz + tt0 - 1];
    }
    __syncthreads();
    #pragma unroll
    for (int r = 0; r < 16; r++) {
        int tr = r * 4 + rowq;   // t within tile
        int dc = colt;           // d within tile
        float v0 = Xs[dc][tr];       // x[t-1]
        float v1 = Xs[dc][tr + 1];   // x[t]
        unsigned pack = (unsigned)f2bf(v0) | ((unsigned)f2bf(v1) << 16);
        int m = (b << 10) + tt0 + tr;
        ((unsigned*)a2)[(size_t)m * (K2 / 2) + dd0 + dc] = pack;
    }
}

// 128x128-tile bf16 MFMA GEMM with fused bias + activation epilogue.
// A [M,2048] bf16 row-major; Bt [N,2048] bf16 row-major (= conv_w cast).
// Writes: z(tanh) -> zc (=d_out c area), f(sigm) -> fh (=d_out h area), o(sigm) -> ob bf16 ws.
#define LDK 72   // LDS pitch: 144 B rows, 16B-aligned, 2-way-free bank pattern
__global__ __launch_bounds__(256)
void gemm_gates(const unsigned short* __restrict__ A, const unsigned short* __restrict__ Bt,
                const float* __restrict__ bias,
                float* __restrict__ zc, float* __restrict__ fh, unsigned short* __restrict__ ob) {
    __shared__ __align__(16) unsigned short As[128 * LDK];
    __shared__ __align__(16) unsigned short Bs2[128 * LDK];
    int tid = threadIdx.x;
    int n0 = blockIdx.x << 7;   // 24 n-tiles
    int m0 = blockIdx.y << 7;   // 128 m-tiles
    int wave = tid >> 6, lane = tid & 63;
    int wm = wave & 1, wn = wave >> 1;     // 2x2 waves -> 64x64 each
    int lm = lane & 15, q = lane >> 4;
    f32x4 acc[4][4] = {};
    const size_t abase = (size_t)m0 * K2;
    const size_t bbase = (size_t)n0 * K2;
    for (int kb = 0; kb < K2; kb += 64) {
        #pragma unroll
        for (int i = 0; i < 4; i++) {
            int lid = i * 256 + tid;       // 1024 16B-chunks per tile
            int row = lid >> 3;
            int col = (lid & 7) << 3;
            *(u16x8*)&As[row * LDK + col]  = *(const u16x8*)&A[abase + (size_t)row * K2 + kb + col];
            *(u16x8*)&Bs2[row * LDK + col] = *(const u16x8*)&Bt[bbase + (size_t)row * K2 + kb + col];
        }
        __syncthreads();
        #pragma unroll
        for (int ks = 0; ks < 64; ks += 32) {
            bf16x8 af[4], bfr[4];
            #pragma unroll
            for (int i = 0; i < 4; i++)
                af[i] = *(bf16x8*)&As[(wm * 64 + i * 16 + lm) * LDK + ks + q * 8];
            #pragma unroll
            for (int j = 0; j < 4; j++)
                bfr[j] = *(bf16x8*)&Bs2[(wn * 64 + j * 16 + lm) * LDK + ks + q * 8];
            #pragma unroll
            for (int i = 0; i < 4; i++)
                #pragma unroll
                for (int j = 0; j < 4; j++)
                    acc[i][j] = __builtin_amdgcn_mfma_f32_16x16x32_bf16(af[i], bfr[j], acc[i][j], 0, 0, 0);
        }
        __syncthreads();
    }
    // Epilogue: C/D layout col=lane&15, row=(lane>>4)*4+reg
    int gt = n0 >> 10;   // 0:z(tanh) 1:f(sigm) 2:o(sigm->bf16)
    #pragma unroll
    for (int i = 0; i < 4; i++) {
        int mrow = m0 + wm * 64 + i * 16 + q * 4;
        #pragma unroll
        for (int j = 0; j < 4; j++) {
            int n = n0 + wn * 64 + j * 16 + lm;
            float bv = bias[n];
            int hcol = n & 1023;
            #pragma unroll
            for (int r = 0; r < 4; r++) {
                float g = acc[i][j][r] + bv;
                size_t idx = (size_t)(mrow + r) * Hsz + hcol;
                if (gt == 0) {
                    float e = __expf(2.f * g);
                    zc[idx] = __fdividef(e - 1.f, e + 1.f);
                } else {
                    float s = __fdividef(1.f, 1.f + __expf(-g));
                    if (gt == 1) fh[idx] = s;
                    else         ob[idx] = f2bf(s);
                }
            }
        }
    }
}

// fo-pooling scan: c_t = z + f*(c-z); h = o*c. One thread per (b,h) chain.
// Reads z from zc / f from fh and overwrites in-place (same element, read-before-write).
__global__ __launch_bounds__(64)
void recurrence(float* __restrict__ zc, float* __restrict__ fh,
                const unsigned short* __restrict__ ob) {
    int g = blockIdx.x * 64 + threadIdx.x;   // 16384 chains
    int b = g >> 10, h = g & 1023;
    size_t base = ((size_t)b << 20) + h;     // b*T*H + h
    float c = 0.f;
    #pragma unroll 8
    for (int t = 0; t < Tsz; t++) {
        size_t idx = base + ((size_t)t << 10);
        float z = zc[idx];
        float f = fh[idx];
        float o = bf2f(ob[idx]);
        c = z + f * (c - z);
        zc[idx] = c;
        fh[idx] = o * c;
    }
}

extern "C" void kernel_launch(void* const* d_in, const int* in_sizes, int n_in,
                              void* d_out, int out_size, void* d_ws, size_t ws_size,
                              hipStream_t stream) {
    const float* x    = (const float*)d_in[0];   // [16,1024,1024]
    const float* w    = (const float*)d_in[1];   // [3072,1024,2]
    const float* bias = (const float*)d_in[2];   // [3072]
    float* zc = (float*)d_out;                               // c_seq out (holds z pre-scan)
    float* fh = (float*)d_out + (size_t)Mtot * Hsz;          // h_seq out (holds f pre-scan)
    unsigned short* a2 = (unsigned short*)d_ws;              // 64 MB
    unsigned short* wb = a2 + (size_t)Mtot * K2;             // 12.6 MB
    unsigned short* ob = wb + (size_t)Ntot * K2;             // 32 MB (o gate, bf16)

    hipLaunchKernelGGL(prep_w, dim3(6144), dim3(256), 0, stream, w, wb);
    hipLaunchKernelGGL(prep_a, dim3(4096), dim3(256), 0, stream, x, a2);
    hipLaunchKernelGGL(gemm_gates, dim3(24, 128), dim3(256), 0, stream, a2, wb, bias, zc, fh, ob);
    hipLaunchKernelGGL(recurrence, dim3(256), dim3(64), 0, stream, zc, fh, ob);
}

// Round 2
// 517.634 us; speedup vs baseline: 1.0773x; 1.0773x over previous
//
#include <hip/hip_runtime.h>

// Problem constants
#define Bsz 16
#define Dch 1024
#define Tsz 1024
#define Hsz 1024
#define Mtot (Bsz*Tsz)   // 16384
#define K2   (2*Dch)     // 2048
#define Ntot (3*Hsz)     // 3072
#define NCH  16          // scan chunks per chain
#define CL   64          // chunk length (NCH*CL == Tsz)

typedef __attribute__((ext_vector_type(8))) short bf16x8;
typedef __attribute__((ext_vector_type(4))) float f32x4;

__device__ __forceinline__ unsigned short f2bf(float x) {
    unsigned u = __float_as_uint(x);
    u += 0x7FFFu + ((u >> 16) & 1u);   // round-to-nearest-even
    return (unsigned short)(u >> 16);
}
__device__ __forceinline__ float bf2f(unsigned short s) {
    return __uint_as_float(((unsigned)s) << 16);
}

// async global->LDS, 16B per lane, dest = ldsbase + lane*16 (wave-uniform base)
#define GLOAD_LDS16(gp, lp) \
    __builtin_amdgcn_global_load_lds((const __attribute__((address_space(1))) void*)(gp), \
                                     (__attribute__((address_space(3))) void*)(lp), 16, 0, 0)

// conv_w [3072,1024,2] fp32 -> bf16. Flat layout IS B^T[n][kk] row-major already.
__global__ void prep_w(const float* __restrict__ w, unsigned short* __restrict__ wb) {
    int i = blockIdx.x * blockDim.x + threadIdx.x;   // one float4 per thread
    float4 v = ((const float4*)w)[i];
    ushort4 r;
    r.x = f2bf(v.x); r.y = f2bf(v.y); r.z = f2bf(v.z); r.w = f2bf(v.w);
    ((ushort4*)wb)[i] = r;
}

// inputs [B,D,T] fp32 -> A2 [M=B*T][2048] bf16, A2[b*T+t][2d+k] = x[b,d,t+k-1] (0 at t-1<0)
__global__ void prep_a(const float* __restrict__ x, unsigned short* __restrict__ a2) {
    __shared__ float Xs[64][66];
    int bid = blockIdx.x;
    int b   = bid >> 8;
    int tt0 = ((bid >> 4) & 15) << 6;
    int dd0 = (bid & 15) << 6;
    int tid  = threadIdx.x;
    int colt = tid & 63, rowq = tid >> 6;
    const size_t xbase = (size_t)b * (Dch * Tsz);
    #pragma unroll
    for (int r = 0; r < 16; r++) {
        int dd = r * 4 + rowq;
        Xs[dd][1 + colt] = x[xbase + (size_t)(dd0 + dd) * Tsz + tt0 + colt];
    }
    if (tid < 64) {
        Xs[tid][0] = (tt0 == 0) ? 0.f : x[xbase + (size_t)(dd0 + tid) * Tsz + tt0 - 1];
    }
    __syncthreads();
    #pragma unroll
    for (int r = 0; r < 16; r++) {
        int tr = r * 4 + rowq;
        int dc = colt;
        float v0 = Xs[dc][tr];
        float v1 = Xs[dc][tr + 1];
        unsigned pack = (unsigned)f2bf(v0) | ((unsigned)f2bf(v1) << 16);
        int m = (b << 10) + tt0 + tr;
        ((unsigned*)a2)[(size_t)m * (K2 / 2) + dd0 + dc] = pack;
    }
}

// 128x128-tile bf16 MFMA GEMM, global_load_lds staging with XOR-8 chunk swizzle.
// LDS tiles contiguous [128 rows][64 cols] bf16 (16 KB each, no pad);
// LDS chunk (row, lc) holds global 8-elem chunk (row, lc ^ (row&7)).
__global__ __launch_bounds__(256)
void gemm_gates(const unsigned short* __restrict__ A, const unsigned short* __restrict__ Bt,
                const float* __restrict__ bias,
                float* __restrict__ zc, float* __restrict__ fh, unsigned short* __restrict__ ob) {
    __shared__ __align__(16) unsigned short As[128 * 64];
    __shared__ __align__(16) unsigned short Bs2[128 * 64];
    int tid = threadIdx.x;
    int n0 = blockIdx.x << 7;   // 24 n-tiles
    int m0 = blockIdx.y << 7;   // 128 m-tiles
    int wave = tid >> 6, lane = tid & 63;
    int wm = wave & 1, wn = wave >> 1;     // 2x2 waves -> 64x64 each
    int lm = lane & 15, q = lane >> 4;

    // staging: lane covers (row = base + lane>>3, lds chunk = lane&7)
    int lrow = lane >> 3, lchunk = lane & 7;
    int gch  = lchunk ^ lrow;                 // row&7 == lrow (row bases are %8==0)
    const unsigned short* Ag = A  + (size_t)(m0 + wave * 32 + lrow) * K2 + gch * 8;
    const unsigned short* Bg = Bt + (size_t)(n0 + wave * 32 + lrow) * K2 + gch * 8;

    f32x4 acc[4][4] = {};
    for (int kb = 0; kb < K2; kb += 64) {
        #pragma unroll
        for (int j = 0; j < 4; j++) {         // wave stages rows [wave*32+j*8, +8)
            int rbase = wave * 32 + j * 8;
            GLOAD_LDS16(Ag + (size_t)j * 8 * K2 + kb, &As[rbase * 64]);
            GLOAD_LDS16(Bg + (size_t)j * 8 * K2 + kb, &Bs2[rbase * 64]);
        }
        __syncthreads();
        #pragma unroll
        for (int ks = 0; ks < 64; ks += 32) {
            bf16x8 af[4], bfr[4];
            int cs = ks >> 3;                  // chunk base (0 or 4)
            int sw = (lm & 7);                 // xor key = row&7 = lm&7
            #pragma unroll
            for (int i = 0; i < 4; i++)
                af[i] = *(bf16x8*)&As[(wm * 64 + i * 16 + lm) * 64 + (((cs + q) ^ sw) << 3)];
            #pragma unroll
            for (int j = 0; j < 4; j++)
                bfr[j] = *(bf16x8*)&Bs2[(wn * 64 + j * 16 + lm) * 64 + (((cs + q) ^ sw) << 3)];
            #pragma unroll
            for (int i = 0; i < 4; i++)
                #pragma unroll
                for (int j = 0; j < 4; j++)
                    acc[i][j] = __builtin_amdgcn_mfma_f32_16x16x32_bf16(af[i], bfr[j], acc[i][j], 0, 0, 0);
        }
        __syncthreads();
    }
    // Epilogue: C/D layout col=lane&15, row=(lane>>4)*4+reg
    int gt = n0 >> 10;   // 0:z(tanh) 1:f(sigm) 2:o(sigm->bf16)
    #pragma unroll
    for (int i = 0; i < 4; i++) {
        int mrow = m0 + wm * 64 + i * 16 + q * 4;
        #pragma unroll
        for (int j = 0; j < 4; j++) {
            int n = n0 + wn * 64 + j * 16 + lm;
            float bv = bias[n];
            int hcol = n & 1023;
            #pragma unroll
            for (int r = 0; r < 4; r++) {
                float g = acc[i][j][r] + bv;
                size_t idx = (size_t)(mrow + r) * Hsz + hcol;
                if (gt == 0) {
                    float e = __expf(2.f * g);
                    zc[idx] = __fdividef(e - 1.f, e + 1.f);
                } else {
                    float s = __fdividef(1.f, 1.f + __expf(-g));
                    if (gt == 1) fh[idx] = s;
                    else         ob[idx] = f2bf(s);
                }
            }
        }
    }
}

// ---- chunked fo-pooling scan: c_t = z + f*(c - z), c_0 = 0 ----
// Pass 1: per-chunk affine (a = prod f, b = chunk result from c_in=0)
__global__ __launch_bounds__(256)
void scan1(const float* __restrict__ zc, const float* __restrict__ fh,
           float* __restrict__ Aw, float* __restrict__ Bw) {
    int blk = blockIdx.x;                 // 16 b * 16 ch * 4 hb
    int hb = blk & 3, ch = (blk >> 2) & 15, b = blk >> 6;
    int h = hb * 256 + threadIdx.x;
    size_t base = ((size_t)b << 20) + ((size_t)(ch * CL) << 10) + h;
    float a = 1.f, bb = 0.f;
    #pragma unroll 8
    for (int s = 0; s < CL; s++) {
        size_t idx = base + ((size_t)s << 10);
        float z = zc[idx], f = fh[idx];
        a *= f;
        bb = z + f * (bb - z);
    }
    int o = (ch * Bsz + b) * Hsz + h;
    Aw[o] = a; Bw[o] = bb;
}

// Pass 2: sequential combine over 16 chunks -> c entering each chunk
__global__ __launch_bounds__(256)
void scan2(const float* __restrict__ Aw, const float* __restrict__ Bw,
           float* __restrict__ C0) {
    int g = blockIdx.x * 256 + threadIdx.x;   // 16384 chains
    int b = g >> 10, h = g & 1023;
    float c = 0.f;
    #pragma unroll
    for (int ch = 0; ch < NCH; ch++) {
        int o = (ch * Bsz + b) * Hsz + h;
        C0[o] = c;
        c = Aw[o] * c + Bw[o];
    }
}

// Pass 3: apply with correct c0; write c_seq and h_seq in place of z/f.
__global__ __launch_bounds__(256)
void scan3(float* __restrict__ zc, float* __restrict__ fh,
           const unsigned short* __restrict__ ob, const float* __restrict__ C0) {
    int blk = blockIdx.x;
    int hb = blk & 3, ch = (blk >> 2) & 15, b = blk >> 6;
    int h = hb * 256 + threadIdx.x;
    size_t base = ((size_t)b << 20) + ((size_t)(ch * CL) << 10) + h;
    float c = C0[(ch * Bsz + b) * Hsz + h];
    #pragma unroll 8
    for (int s = 0; s < CL; s++) {
        size_t idx = base + ((size_t)s << 10);
        float z = zc[idx];
        float f = fh[idx];
        float o = bf2f(ob[idx]);
        c = z + f * (c - z);
        zc[idx] = c;
        fh[idx] = o * c;
    }
}

extern "C" void kernel_launch(void* const* d_in, const int* in_sizes, int n_in,
                              void* d_out, int out_size, void* d_ws, size_t ws_size,
                              hipStream_t stream) {
    const float* x    = (const float*)d_in[0];   // [16,1024,1024]
    const float* w    = (const float*)d_in[1];   // [3072,1024,2]
    const float* bias = (const float*)d_in[2];   // [3072]
    float* zc = (float*)d_out;                               // c_seq out (holds z pre-scan)
    float* fh = (float*)d_out + (size_t)Mtot * Hsz;          // h_seq out (holds f pre-scan)
    unsigned short* a2 = (unsigned short*)d_ws;              // 64 MB
    unsigned short* wb = a2 + (size_t)Mtot * K2;             // 12.6 MB
    unsigned short* ob = wb + (size_t)Ntot * K2;             // 32 MB (o gate, bf16)
    float* Aw = (float*)(ob + (size_t)Mtot * Hsz);           // 1 MB
    float* Bw = Aw + NCH * Bsz * Hsz;                        // 1 MB
    float* C0 = Bw + NCH * Bsz * Hsz;                        // 1 MB

    hipLaunchKernelGGL(prep_w, dim3(6144), dim3(256), 0, stream, w, wb);
    hipLaunchKernelGGL(prep_a, dim3(4096), dim3(256), 0, stream, x, a2);
    hipLaunchKernelGGL(gemm_gates, dim3(24, 128), dim3(256), 0, stream, a2, wb, bias, zc, fh, ob);
    hipLaunchKernelGGL(scan1, dim3(1024), dim3(256), 0, stream, zc, fh, Aw, Bw);
    hipLaunchKernelGGL(scan2, dim3(64), dim3(256), 0, stream, Aw, Bw, C0);
    hipLaunchKernelGGL(scan3, dim3(1024), dim3(256), 0, stream, zc, fh, ob, C0);
}

// Round 3
// 510.658 us; speedup vs baseline: 1.0920x; 1.0137x over previous
//
#include <hip/hip_runtime.h>

// Problem constants
#define Bsz 16
#define Dch 1024
#define Tsz 1024
#define Hsz 1024
#define Mtot (Bsz*Tsz)   // 16384
#define K2   (2*Dch)     // 2048
#define Ntot (3*Hsz)     // 3072
#define NCH  16          // scan chunks per chain
#define CL   64          // chunk length (NCH*CL == Tsz)

typedef __attribute__((ext_vector_type(8))) short bf16x8;
typedef __attribute__((ext_vector_type(4))) float f32x4;

__device__ __forceinline__ unsigned short f2bf(float x) {
    unsigned u = __float_as_uint(x);
    u += 0x7FFFu + ((u >> 16) & 1u);   // round-to-nearest-even
    return (unsigned short)(u >> 16);
}
__device__ __forceinline__ float bf2f(unsigned short s) {
    return __uint_as_float(((unsigned)s) << 16);
}

// async global->LDS, 16B per lane, dest = ldsbase + lane*16 (wave-uniform base)
#define GLOAD_LDS16(gp, lp) \
    __builtin_amdgcn_global_load_lds((const __attribute__((address_space(1))) void*)(gp), \
                                     (__attribute__((address_space(3))) void*)(lp), 16, 0, 0)

// Merged prep: blocks [0,4096) build A2 (LDS transpose + causal shift + bf16 pack);
// blocks [4096,5632) cast conv_w fp32->bf16 (flat layout IS B^T row-major already).
__global__ __launch_bounds__(256)
void prep(const float* __restrict__ x, unsigned short* __restrict__ a2,
          const float* __restrict__ w, unsigned short* __restrict__ wb) {
    __shared__ float Xs[64][66];
    int bid = blockIdx.x;
    int tid = threadIdx.x;
    if (bid >= 4096) {
        // prep_w: 1536 blocks * 256 thr * 4 float4 = 1,572,864 float4s
        int i0 = (bid - 4096) * 256 + tid;
        #pragma unroll
        for (int k = 0; k < 4; k++) {
            int i = i0 + k * (1536 * 256);
            float4 v = ((const float4*)w)[i];
            ushort4 r;
            r.x = f2bf(v.x); r.y = f2bf(v.y); r.z = f2bf(v.z); r.w = f2bf(v.w);
            ((ushort4*)wb)[i] = r;
        }
        return;
    }
    int b   = bid >> 8;
    int tt0 = ((bid >> 4) & 15) << 6;
    int dd0 = (bid & 15) << 6;
    int colt = tid & 63, rowq = tid >> 6;
    const size_t xbase = (size_t)b * (Dch * Tsz);
    #pragma unroll
    for (int r = 0; r < 16; r++) {
        int dd = r * 4 + rowq;
        Xs[dd][1 + colt] = x[xbase + (size_t)(dd0 + dd) * Tsz + tt0 + colt];
    }
    if (tid < 64) {
        Xs[tid][0] = (tt0 == 0) ? 0.f : x[xbase + (size_t)(dd0 + tid) * Tsz + tt0 - 1];
    }
    __syncthreads();
    #pragma unroll
    for (int r = 0; r < 16; r++) {
        int tr = r * 4 + rowq;
        int dc = colt;
        float v0 = Xs[dc][tr];       // x[t-1]
        float v1 = Xs[dc][tr + 1];   // x[t]
        unsigned pack = (unsigned)f2bf(v0) | ((unsigned)f2bf(v1) << 16);
        int m = (b << 10) + tt0 + tr;
        ((unsigned*)a2)[(size_t)m * (K2 / 2) + dd0 + dc] = pack;
    }
}

// 128x128-tile bf16 MFMA GEMM, global_load_lds staging with XOR-8 chunk swizzle.
// LDS chunk (row, lc) holds global 8-elem chunk (row, lc ^ (row&7)) -> 0 bank conflicts.
__global__ __launch_bounds__(256)
void gemm_gates(const unsigned short* __restrict__ A, const unsigned short* __restrict__ Bt,
                const float* __restrict__ bias,
                float* __restrict__ zc, float* __restrict__ fh, unsigned short* __restrict__ ob) {
    __shared__ __align__(16) unsigned short As[128 * 64];
    __shared__ __align__(16) unsigned short Bs2[128 * 64];
    int tid = threadIdx.x;
    int n0 = blockIdx.x << 7;   // 24 n-tiles
    int m0 = blockIdx.y << 7;   // 128 m-tiles
    int wave = tid >> 6, lane = tid & 63;
    int wm = wave & 1, wn = wave >> 1;     // 2x2 waves -> 64x64 each
    int lm = lane & 15, q = lane >> 4;

    int lrow = lane >> 3, lchunk = lane & 7;
    int gch  = lchunk ^ lrow;
    const unsigned short* Ag = A  + (size_t)(m0 + wave * 32 + lrow) * K2 + gch * 8;
    const unsigned short* Bg = Bt + (size_t)(n0 + wave * 32 + lrow) * K2 + gch * 8;

    f32x4 acc[4][4] = {};
    for (int kb = 0; kb < K2; kb += 64) {
        #pragma unroll
        for (int j = 0; j < 4; j++) {
            int rbase = wave * 32 + j * 8;
            GLOAD_LDS16(Ag + (size_t)j * 8 * K2 + kb, &As[rbase * 64]);
            GLOAD_LDS16(Bg + (size_t)j * 8 * K2 + kb, &Bs2[rbase * 64]);
        }
        __syncthreads();
        #pragma unroll
        for (int ks = 0; ks < 64; ks += 32) {
            bf16x8 af[4], bfr[4];
            int cs = ks >> 3;
            int sw = (lm & 7);
            #pragma unroll
            for (int i = 0; i < 4; i++)
                af[i] = *(bf16x8*)&As[(wm * 64 + i * 16 + lm) * 64 + (((cs + q) ^ sw) << 3)];
            #pragma unroll
            for (int j = 0; j < 4; j++)
                bfr[j] = *(bf16x8*)&Bs2[(wn * 64 + j * 16 + lm) * 64 + (((cs + q) ^ sw) << 3)];
            #pragma unroll
            for (int i = 0; i < 4; i++)
                #pragma unroll
                for (int j = 0; j < 4; j++)
                    acc[i][j] = __builtin_amdgcn_mfma_f32_16x16x32_bf16(af[i], bfr[j], acc[i][j], 0, 0, 0);
        }
        __syncthreads();
    }
    // Epilogue: C/D layout col=lane&15, row=(lane>>4)*4+reg
    int gt = n0 >> 10;   // 0:z(tanh) 1:f(sigm) 2:o(sigm->bf16)
    #pragma unroll
    for (int i = 0; i < 4; i++) {
        int mrow = m0 + wm * 64 + i * 16 + q * 4;
        #pragma unroll
        for (int j = 0; j < 4; j++) {
            int n = n0 + wn * 64 + j * 16 + lm;
            float bv = bias[n];
            int hcol = n & 1023;
            #pragma unroll
            for (int r = 0; r < 4; r++) {
                float g = acc[i][j][r] + bv;
                size_t idx = (size_t)(mrow + r) * Hsz + hcol;
                if (gt == 0) {
                    float e = __expf(2.f * g);
                    zc[idx] = __fdividef(e - 1.f, e + 1.f);
                } else {
                    float s = __fdividef(1.f, 1.f + __expf(-g));
                    if (gt == 1) fh[idx] = s;
                    else         ob[idx] = f2bf(s);
                }
            }
        }
    }
}

// ---- chunked fo-pooling scan: c_t = z + f*(c - z), c_0 = 0 ----
// Pass 1: per-chunk affine (a = prod f, b = chunk result from c_in=0), 2 chains/thread
__global__ __launch_bounds__(256)
void scan1(const float* __restrict__ zc, const float* __restrict__ fh,
           float* __restrict__ Aw, float* __restrict__ Bw) {
    int blk = blockIdx.x;                 // 16 b * 16 ch * 2 hb = 512
    int hb = blk & 1, ch = (blk >> 1) & 15, b = blk >> 5;
    int h = hb * 512 + threadIdx.x * 2;
    size_t base = ((size_t)b << 20) + ((size_t)(ch * CL) << 10) + h;
    float ax = 1.f, ay = 1.f, bx = 0.f, by = 0.f;
    #pragma unroll 8
    for (int s = 0; s < CL; s++) {
        size_t idx = base + ((size_t)s << 10);
        float2 z = *(const float2*)&zc[idx];
        float2 f = *(const float2*)&fh[idx];
        ax *= f.x; ay *= f.y;
        bx = z.x + f.x * (bx - z.x);
        by = z.y + f.y * (by - z.y);
    }
    int o = (ch * Bsz + b) * Hsz + h;
    *(float2*)&Aw[o] = make_float2(ax, ay);
    *(float2*)&Bw[o] = make_float2(bx, by);
}

// Pass 2 (merged prefix + apply): block computes its own chunk-entry c0 from Aw/Bw
// (block-uniform short loop, L2-hot), then applies the recurrence in place:
// zc: z -> c_seq, fh: f -> h_seq.
__global__ __launch_bounds__(256)
void scan3(float* __restrict__ zc, float* __restrict__ fh,
           const unsigned short* __restrict__ ob,
           const float* __restrict__ Aw, const float* __restrict__ Bw) {
    int blk = blockIdx.x;                 // 512
    int hb = blk & 1, ch = (blk >> 1) & 15, b = blk >> 5;
    int h = hb * 512 + threadIdx.x * 2;
    float cx = 0.f, cy = 0.f;
    for (int cp = 0; cp < ch; cp++) {     // chunk-entry state (block-uniform trip)
        int o = (cp * Bsz + b) * Hsz + h;
        float2 A = *(const float2*)&Aw[o];
        float2 B = *(const float2*)&Bw[o];
        cx = A.x * cx + B.x;
        cy = A.y * cy + B.y;
    }
    size_t base = ((size_t)b << 20) + ((size_t)(ch * CL) << 10) + h;
    #pragma unroll 8
    for (int s = 0; s < CL; s++) {
        size_t idx = base + ((size_t)s << 10);
        float2 z = *(const float2*)&zc[idx];
        float2 f = *(const float2*)&fh[idx];
        unsigned ov = *(const unsigned*)&ob[idx];   // two bf16 o-gates
        cx = z.x + f.x * (cx - z.x);
        cy = z.y + f.y * (cy - z.y);
        *(float2*)&zc[idx] = make_float2(cx, cy);
        float ox = bf2f((unsigned short)(ov & 0xFFFF));
        float oy = bf2f((unsigned short)(ov >> 16));
        *(float2*)&fh[idx] = make_float2(ox * cx, oy * cy);
    }
}

extern "C" void kernel_launch(void* const* d_in, const int* in_sizes, int n_in,
                              void* d_out, int out_size, void* d_ws, size_t ws_size,
                              hipStream_t stream) {
    const float* x    = (const float*)d_in[0];   // [16,1024,1024]
    const float* w    = (const float*)d_in[1];   // [3072,1024,2]
    const float* bias = (const float*)d_in[2];   // [3072]
    float* zc = (float*)d_out;                               // c_seq out (holds z pre-scan)
    float* fh = (float*)d_out + (size_t)Mtot * Hsz;          // h_seq out (holds f pre-scan)
    unsigned short* a2 = (unsigned short*)d_ws;              // 64 MB
    unsigned short* wb = a2 + (size_t)Mtot * K2;             // 12.6 MB
    unsigned short* ob = wb + (size_t)Ntot * K2;             // 32 MB (o gate, bf16)
    float* Aw = (float*)(ob + (size_t)Mtot * Hsz);           // 1 MB
    float* Bw = Aw + NCH * Bsz * Hsz;                        // 1 MB

    hipLaunchKernelGGL(prep, dim3(5632), dim3(256), 0, stream, x, a2, w, wb);
    hipLaunchKernelGGL(gemm_gates, dim3(24, 128), dim3(256), 0, stream, a2, wb, bias, zc, fh, ob);
    hipLaunchKernelGGL(scan1, dim3(512), dim3(256), 0, stream, zc, fh, Aw, Bw);
    hipLaunchKernelGGL(scan3, dim3(512), dim3(256), 0, stream, zc, fh, ob, Aw, Bw);
}